// Round 7
// baseline (468.019 us; speedup 1.0000x reference)
//
#include <hip/hip_runtime.h>
#include <hip/hip_bf16.h>

// ELSA block. Inputs: float32. Output: float32. Internal: bf16 (MFMA).
// Pipeline:
//  k_prep: weight repack f32->bf16 (interleave q/k rows, pad, fold ghost, swizzle conv w)
//  k_gemm<0>: LN fused + qkv projection (MFMA, cot-loop) -> h=(q*k*scale), v
//  k_conv: grouped 7x7 conv + exact GELU, sliding-window, 16-row tiles
//  2 chunks of 8 frames:  k_gemm<1>: 294-ch logits + ghost -> attn_c (8f,294,p)
//                         k_aggr: 49-tap window aggregation -> out_t rows
//  k_gemm<2>: out proj + bias + f32 residual -> d_out f32 (B,C,D,H,W)
// Workspace (bytes), total 128,512,512 (~122.6 MB):
//  [0)        W2 (320x96 bf16)  61,440
//  [61440)    bias2 (320 f32)    1,280
//  [62720)    WA2 (320x96 bf16) 61,440
//  [124160)   biasA2 (320 f32)   1,280
//  [125440)   WP (128x96 bf16)  24,576
//  [150016)   biasP (128 f32)      512
//  [150528)   WC1 (24x4x7x7x4 f32) 75,264
//  [225792)   a_t          28,311,552
//  [28537344) h / out_t    28,311,552
//  [56848896) v            28,311,552
//  [85160448) attn_c (8x294x9216 bf16) 43,352,064

typedef unsigned short u16;
typedef short bf16x8 __attribute__((ext_vector_type(8)));
typedef float floatx4 __attribute__((ext_vector_type(4)));
typedef unsigned short ushort4v __attribute__((ext_vector_type(4)));
typedef unsigned int uint4v __attribute__((ext_vector_type(4)));

#define PIX      9216
#define SCALE_QK 0.25f

__device__ __forceinline__ float b2f(u16 u) {
  union { unsigned int i; float f; } z; z.i = ((unsigned int)u) << 16; return z.f;
}
__device__ __forceinline__ float lo2f(unsigned int u) {
  union { unsigned int i; float f; } z; z.i = u << 16; return z.f;
}
__device__ __forceinline__ float hi2f(unsigned int u) {
  union { unsigned int i; float f; } z; z.i = u & 0xFFFF0000u; return z.f;
}
__device__ __forceinline__ u16 f2b(float f) {
  union { float f; unsigned int i; } z; z.f = f;
  unsigned int r = z.i + 0x7fffu + ((z.i >> 16) & 1u);
  return (u16)(r >> 16);
}

// ---------------- weight prep (f32 in, bf16/f32 out) ----------------
__global__ void k_prep(const float* __restrict__ w_qk, const float* __restrict__ b_qk,
                       const float* __restrict__ w_v,  const float* __restrict__ b_v,
                       const float* __restrict__ w_a1,
                       const float* __restrict__ w_a2, const float* __restrict__ b_a2,
                       const float* __restrict__ g_mul,const float* __restrict__ g_add,
                       const float* __restrict__ w_p,  const float* __restrict__ b_p,
                       u16* __restrict__ W2, float* __restrict__ bias2,
                       u16* __restrict__ WA2, float* __restrict__ biasA2,
                       u16* __restrict__ WP, float* __restrict__ biasP,
                       float* __restrict__ WC1) {
  int i = blockIdx.x * 256 + threadIdx.x;
  if (i < 30720) {                       // W2: 320*96
    int r = i / 96, ci = i % 96;
    float val = 0.f;
    if (r < 192) { int src = (r & 1) ? (96 + (r >> 1)) : (r >> 1); val = w_qk[src * 96 + ci]; }
    else if (r < 288) val = w_v[(r - 192) * 96 + ci];
    W2[i] = f2b(val);
  } else if (i < 31040) {                // bias2: 320
    int r = i - 30720; float bv = 0.f;
    if (r < 192) { int src = (r & 1) ? (96 + (r >> 1)) : (r >> 1); bv = b_qk[src]; }
    else if (r < 288) bv = b_v[r - 192];
    bias2[r] = bv;
  } else if (i < 61760) {                // WA2: 320*96
    int j = i - 31040; int r = j / 96, ci = j % 96;
    float wv = 0.f;
    if (r < 294) wv = w_a2[r * 96 + ci] * g_mul[r];
    WA2[j] = f2b(wv);
  } else if (i < 62080) {                // biasA2: 320
    int r = i - 61760; float bv = 0.f;
    if (r < 294) bv = b_a2[r] * g_mul[r] + g_add[r];
    biasA2[r] = bv;
  } else if (i < 74368) {                // WP: 128*96
    int j = i - 62080; int r = j / 96;
    WP[j] = (r < 96) ? f2b(w_p[j]) : (u16)0;
  } else if (i < 74496) {                // biasP: 128
    int r = i - 74368;
    biasP[r] = (r < 96) ? b_p[r] : 0.f;
  } else if (i < 93312) {                // WC1: [g][ch][ky][kx][co] f32, 18816
    int j = i - 74496;
    int co = j & 3, kx = (j >> 2) % 7, ky = (j / 28) % 7, ch = (j / 196) & 3, g = j / 784;
    WC1[j] = w_a1[(g * 4 + co) * 196 + ch * 49 + ky * 7 + kx];
  }
}

// ---------------- MFMA GEMM, cot-loop inside, 64px tile, K=96 ----------------
// MODE 0: LN fused from x f32; -> h (out0), v (out1). f = blockIdx.y.
// MODE 1: X = a_t; -> attn chunk out0, f = fArg + blockIdx.y (store frame-local).
// MODE 2: X = out_t; -> outF = d_out f32 with resid = x. f = blockIdx.y.
template <int MODE>
__global__ __launch_bounds__(256) void k_gemm(const float* __restrict__ xf,
                                              const float* __restrict__ lg,
                                              const float* __restrict__ lb,
                                              const u16* __restrict__ X,
                                              const u16* __restrict__ W,
                                              const float* __restrict__ bias,
                                              u16* __restrict__ out0,
                                              u16* __restrict__ out1,
                                              float* __restrict__ outF,
                                              const float* __restrict__ resid,
                                              int fArg) {
  __shared__ u16 lx[64 * 104];    // X tile, (pixel row, 96ch), stride 104 (16B align)
  const int tid = threadIdx.x;
  const int fc = blockIdx.y;
  const int f = (MODE == 1) ? (fArg + fc) : fc;
  const int p0 = blockIdx.x * 64;

  if constexpr (MODE == 0) {
    __shared__ float ls[96 * 65];   // f32 x tile (c,p), stride 65 kills conflicts
    __shared__ float mu_s[64], rs_s[64];
    const int b = f >> 3, d = f & 7;
    const size_t xbase = ((size_t)(b * 768 + d)) * PIX + p0;  // + c*73728
    for (int idx = tid; idx < 6144; idx += 256) {
      int c = idx >> 6, r = idx & 63;
      ls[c * 65 + r] = xf[xbase + (size_t)c * 73728 + r];
    }
    __syncthreads();
    if (tid < 64) {
      float s = 0.f, ss = 0.f;
      for (int c = 0; c < 96; ++c) { float v = ls[c * 65 + tid]; s += v; ss += v * v; }
      float mu = s * (1.f / 96.f);
      float var = ss * (1.f / 96.f) - mu * mu;
      mu_s[tid] = mu; rs_s[tid] = rsqrtf(var + 1e-5f);
    }
    __syncthreads();
    {
      int pl = tid & 63, q = tid >> 6;        // 4 threads/pixel, 24 ch each
      float mu = mu_s[pl], rs = rs_s[pl];
      #pragma unroll
      for (int t = 0; t < 12; ++t) {
        int c = q * 24 + 2 * t;
        float v0 = (ls[c * 65 + pl] - mu) * rs * lg[c] + lb[c];
        float v1 = (ls[(c + 1) * 65 + pl] - mu) * rs * lg[c + 1] + lb[c + 1];
        unsigned int pack = (unsigned int)f2b(v0) | ((unsigned int)f2b(v1) << 16);
        *(unsigned int*)&lx[pl * 104 + c] = pack;
      }
    }
    __syncthreads();
  } else {
    for (int ch = tid; ch < 768; ch += 256) {
      int r = ch / 12, s2 = ch % 12;
      *(uint4v*)&lx[r * 104 + s2 * 8] =
          *(const uint4v*)&X[((size_t)(f * PIX + p0 + r)) * 96 + s2 * 8];
    }
    __syncthreads();
  }

  const int lane = tid & 63, wv = tid >> 6;
  const int cw = (wv >> 1) * 32, pw = (wv & 1) * 32;
  const int m = lane & 15, quad = lane >> 4;

  // B fragments: loop-invariant across cot
  bf16x8 bfr[2][3];
  #pragma unroll
  for (int ks = 0; ks < 3; ++ks) {
    int ko = ks * 32 + quad * 8;
    bfr[0][ks] = *(const bf16x8*)&lx[(pw + m) * 104 + ko];
    bfr[1][ks] = *(const bf16x8*)&lx[(pw + 16 + m) * 104 + ko];
  }

  const int NCOT = (MODE == 2) ? 2 : 5;
  for (int cot = 0; cot < NCOT; ++cot) {
    floatx4 acc[2][2] = {};
    #pragma unroll
    for (int ks = 0; ks < 3; ++ks) {
      int ko = ks * 32 + quad * 8;
      bf16x8 a0 = *(const bf16x8*)&W[(size_t)(cot * 64 + cw + m) * 96 + ko];
      bf16x8 a1 = *(const bf16x8*)&W[(size_t)(cot * 64 + cw + 16 + m) * 96 + ko];
      acc[0][0] = __builtin_amdgcn_mfma_f32_16x16x32_bf16(a0, bfr[0][ks], acc[0][0], 0, 0, 0);
      acc[0][1] = __builtin_amdgcn_mfma_f32_16x16x32_bf16(a0, bfr[1][ks], acc[0][1], 0, 0, 0);
      acc[1][0] = __builtin_amdgcn_mfma_f32_16x16x32_bf16(a1, bfr[0][ks], acc[1][0], 0, 0, 0);
      acc[1][1] = __builtin_amdgcn_mfma_f32_16x16x32_bf16(a1, bfr[1][ks], acc[1][1], 0, 0, 0);
    }

    for (int mt = 0; mt < 2; ++mt)
      for (int nt = 0; nt < 2; ++nt) {
        int R = cot * 64 + cw + mt * 16 + quad * 4;
        int pc = p0 + pw + nt * 16 + m;
        floatx4 v4 = acc[mt][nt];
        if (MODE == 0) {
          if (cot < 3) {   // interleaved q/k rows: (q_c, k_c, q_{c+1}, k_{c+1})
            float q0 = v4[0] + bias[R + 0], k0 = v4[1] + bias[R + 1];
            float q1 = v4[2] + bias[R + 2], k1 = v4[3] + bias[R + 3];
            int hc = R >> 1;
            out0[((size_t)f * 96 + hc) * PIX + pc]     = f2b(q0 * k0 * SCALE_QK);
            out0[((size_t)f * 96 + hc + 1) * PIX + pc] = f2b(q1 * k1 * SCALE_QK);
          } else {
            for (int r = 0; r < 4; ++r) {
              int vr = R + r - 192;
              if (vr < 96) out1[((size_t)f * 96 + vr) * PIX + pc] = f2b(v4[r] + bias[R + r]);
            }
          }
        } else if (MODE == 1) {
          for (int r = 0; r < 4; ++r) {
            int o = R + r;
            if (o < 294) out0[((size_t)fc * 294 + o) * PIX + pc] = f2b(v4[r] + bias[o]);
          }
        } else {
          int b = f >> 3, d = f & 7;
          for (int r = 0; r < 4; ++r) {
            int o = R + r;
            if (o < 96) {
              size_t gi = ((size_t)(b * 96 + o) * 8 + d) * PIX + pc;
              outF[gi] = resid[gi] + v4[r] + bias[o];
            }
          }
        }
      }
  }
}

// ---------------- grouped 7x7 conv + GELU (sliding window, bf16 LDS) ----------
// h: (f, 96, 9216) bf16 -> a_t: (f*9216+p, 96) bf16.
// block = (group g of 4 ch, 16-row tile, frame). thread = (y of 16, xseg of 6).
__global__ __launch_bounds__(256) void k_conv(const u16* __restrict__ h,
                                              const float* __restrict__ wc1,
                                              const float* __restrict__ b_a1,
                                              u16* __restrict__ a_t) {
  __shared__ u16 li[4 * 22 * 104];   // 4 ch x rows y0-3..y0+18 x cols -3..100, 18.3KB
  const int g = blockIdx.x, ty = blockIdx.y, f = blockIdx.z;
  const int tid = threadIdx.x;
  const int gb = g * 4, y0 = ty * 16;
  for (int idx = tid; idx < 4 * 22 * 104; idx += 256) {
    int col = idx % 104;
    int rr = (idx / 104) % 22;
    int ch = idx / (104 * 22);
    int ax = col - 3, ay = y0 - 3 + rr;
    u16 v = 0;
    if (ax >= 0 && ax < 96 && ay >= 0 && ay < 96)
      v = h[((size_t)f * 96 + gb + ch) * PIX + ay * 96 + ax];
    li[idx] = v;
  }
  __syncthreads();

  const int y = tid >> 4;            // 0..15
  const int x0 = (tid & 15) * 6;     // 0..90 (even -> dword-aligned LDS reads)
  float acc[4][6];
  #pragma unroll
  for (int co = 0; co < 4; ++co) {
    float bv = b_a1[gb + co];
    #pragma unroll
    for (int o = 0; o < 6; ++o) acc[co][o] = bv;
  }

  for (int ch = 0; ch < 4; ++ch)
    for (int ky = 0; ky < 7; ++ky) {
      const float* wrow = &wc1[(((g * 4 + ch) * 7) + ky) * 28];
      float w[28];
      #pragma unroll
      for (int t = 0; t < 28; ++t) w[t] = wrow[t];
      const unsigned int* lsrc =
          (const unsigned int*)&li[(ch * 22 + (y + ky)) * 104 + x0];
      float in[12];
      #pragma unroll
      for (int t = 0; t < 6; ++t) {
        unsigned int u = lsrc[t];
        in[2 * t]     = lo2f(u);
        in[2 * t + 1] = hi2f(u);
      }
      #pragma unroll
      for (int kx = 0; kx < 7; ++kx)
        #pragma unroll
        for (int o = 0; o < 6; ++o)
          #pragma unroll
          for (int co = 0; co < 4; ++co)
            acc[co][o] += w[kx * 4 + co] * in[o + kx];
    }

  size_t obase = ((size_t)f * PIX + (size_t)(y0 + y) * 96 + x0) * 96 + gb;
  #pragma unroll
  for (int o = 0; o < 6; ++o) {
    ushort4v r4;
    #pragma unroll
    for (int co = 0; co < 4; ++co) {
      float a = acc[co][o];
      float ge = 0.5f * a * (1.f + erff(a * 0.70710678118f));
      r4[co] = f2b(ge);
    }
    *(ushort4v*)&a_t[obase + (size_t)o * 96] = r4;
  }
}

// ---------------- 49-tap window aggregation (8-frame chunk) ----------------
// attn_c: (8, 294, 9216) bf16, v: (f, 96, 9216) bf16 -> out_t rows.
__global__ __launch_bounds__(256) void k_aggr(const u16* __restrict__ attn_c,
                                              const u16* __restrict__ v,
                                              u16* __restrict__ out_t,
                                              int fbase) {
  __shared__ u16 lv[4 * 22 * 104];   // 18.3KB
  const int cq = blockIdx.x, ty = blockIdx.y, fc = blockIdx.z;
  const int f = fbase + fc;
  const int tid = threadIdx.x;
  const int c0 = cq * 4, y0 = ty * 16;
  const int head = c0 >> 4;
  for (int idx = tid; idx < 4 * 22 * 104; idx += 256) {
    int col = idx % 104;
    int rr = (idx / 104) % 22;
    int ch = idx / (104 * 22);
    int ax = col - 3, ay = y0 - 3 + rr;
    u16 val = 0;
    if (ax >= 0 && ax < 96 && ay >= 0 && ay < 96)
      val = v[((size_t)f * 96 + c0 + ch) * PIX + ay * 96 + ax];
    lv[idx] = val;
  }
  __syncthreads();

  const int y = tid >> 4;            // 0..15
  const int x0 = (tid & 15) * 6;     // 0..90
  float acc[4][6] = {};
  const int prow = (y0 + y) * 96 + x0;

  for (int i = 0; i < 7; ++i) {
    float vrow[4][12];
    #pragma unroll
    for (int ch = 0; ch < 4; ++ch) {
      const unsigned int* lsrc = (const unsigned int*)&lv[(ch * 22 + (y + i)) * 104 + x0];
      #pragma unroll
      for (int t = 0; t < 6; ++t) {
        unsigned int u = lsrc[t];
        vrow[ch][2 * t]     = lo2f(u);
        vrow[ch][2 * t + 1] = hi2f(u);
      }
    }
    #pragma unroll
    for (int j = 0; j < 7; ++j) {
      const unsigned int* asrc = (const unsigned int*)
          &attn_c[((size_t)fc * 294 + head * 49 + i * 7 + j) * PIX + prow];
      unsigned int u0 = asrc[0], u1 = asrc[1], u2 = asrc[2];
      float av[6] = {lo2f(u0), hi2f(u0), lo2f(u1), hi2f(u1), lo2f(u2), hi2f(u2)};
      #pragma unroll
      for (int o = 0; o < 6; ++o)
        #pragma unroll
        for (int ch = 0; ch < 4; ++ch)
          acc[ch][o] += av[o] * vrow[ch][o + j];
    }
  }

  size_t obase = ((size_t)f * PIX + prow) * 96 + c0;
  #pragma unroll
  for (int o = 0; o < 6; ++o) {
    ushort4v r4;
    #pragma unroll
    for (int ch = 0; ch < 4; ++ch) r4[ch] = f2b(acc[ch][o]);
    *(ushort4v*)&out_t[obase + (size_t)o * 96] = r4;
  }
}

extern "C" void kernel_launch(void* const* d_in, const int* in_sizes, int n_in,
                              void* d_out, int out_size, void* d_ws, size_t ws_size,
                              hipStream_t stream) {
  const float* x    = (const float*)d_in[0];
  const float* ln_g = (const float*)d_in[1];
  const float* ln_b = (const float*)d_in[2];
  const float* w_qk = (const float*)d_in[3];
  const float* b_qk = (const float*)d_in[4];
  const float* w_v  = (const float*)d_in[5];
  const float* b_v  = (const float*)d_in[6];
  const float* w_a1 = (const float*)d_in[7];
  const float* b_a1 = (const float*)d_in[8];
  const float* w_a2 = (const float*)d_in[9];
  const float* b_a2 = (const float*)d_in[10];
  const float* g_mul= (const float*)d_in[11];
  const float* g_add= (const float*)d_in[12];
  const float* w_p  = (const float*)d_in[13];
  const float* b_p  = (const float*)d_in[14];

  char* ws = (char*)d_ws;
  u16*   W2    = (u16*)(ws + 0);
  float* bias2 = (float*)(ws + 61440);
  u16*   WA2   = (u16*)(ws + 62720);
  float* biasA2= (float*)(ws + 124160);
  u16*   WP    = (u16*)(ws + 125440);
  float* biasP = (float*)(ws + 150016);
  float* WC1   = (float*)(ws + 150528);
  u16*   a_t   = (u16*)(ws + 225792);
  u16*   hbuf  = (u16*)(ws + 28537344);     // reused as out_t
  u16*   vbuf  = (u16*)(ws + 56848896);
  u16*   attnc = (u16*)(ws + 85160448);     // 8-frame attn chunk (8 x 294 x 9216)

  k_prep<<<365, 256, 0, stream>>>(w_qk, b_qk, w_v, b_v, w_a1, w_a2, b_a2, g_mul, g_add,
                                  w_p, b_p, W2, bias2, WA2, biasA2, WP, biasP, WC1);
  k_gemm<0><<<dim3(144, 16), 256, 0, stream>>>(x, ln_g, ln_b, nullptr, W2, bias2,
                                               hbuf, vbuf, nullptr, nullptr, 0);
  k_conv<<<dim3(24, 6, 16), 256, 0, stream>>>(hbuf, WC1, b_a1, a_t);
  for (int c = 0; c < 2; ++c) {
    k_gemm<1><<<dim3(144, 8), 256, 0, stream>>>(nullptr, nullptr, nullptr, a_t, WA2,
                                                biasA2, attnc, nullptr, nullptr, nullptr,
                                                c * 8);
    k_aggr<<<dim3(24, 6, 8), 256, 0, stream>>>(attnc, vbuf, hbuf /*out_t*/, c * 8);
  }
  k_gemm<2><<<dim3(144, 16), 256, 0, stream>>>(nullptr, nullptr, nullptr, hbuf /*out_t*/,
                                               WP, biasP, nullptr, nullptr,
                                               (float*)d_out, x, 0);
}